// Round 13
// baseline (283.596 us; speedup 1.0000x reference)
//
#include <hip/hip_runtime.h>
#include <hip/hip_bf16.h>
#include <math.h>

#define DIN 20
#define C 128
#define HC 256
#define EB2 2048
#define MAXNB 400
#define CAP 8192
#define CAPSH 13

typedef unsigned short u16;
typedef unsigned int u32;
typedef unsigned long long u64;
typedef __bf16 bf16x8 __attribute__((ext_vector_type(8)));
typedef float f32x4 __attribute__((ext_vector_type(4)));

__device__ __forceinline__ float bfbits2f(unsigned int lo16) {
    return __uint_as_float(lo16 << 16);
}
__device__ __forceinline__ u16 f2bf_rne(float f) {
    unsigned int b = __float_as_uint(f);
    return (u16)((b + 0x7FFFu + ((b >> 16) & 1u)) >> 16);
}

// exclusive scan of cnt[0..511] -> off[0..511]; wave-shuffle scan, 2 barriers
__device__ __forceinline__ void scan512f(u32* cnt, u32* off, u32* wsum4) {
    int t = threadIdx.x;
    int l = t & 63, w = t >> 6;
    u32 a = cnt[2 * t], b = cnt[2 * t + 1];
    u32 s = a + b;
    u32 isc = s;
    #pragma unroll
    for (int o = 1; o < 64; o <<= 1) {
        u32 n = __shfl_up(isc, o);
        if (l >= o) isc += n;
    }
    if (l == 63) wsum4[w] = isc;
    __syncthreads();
    u32 pre = 0;
    if (w > 0) pre += wsum4[0];
    if (w > 1) pre += wsum4[1];
    if (w > 2) pre += wsum4[2];
    u32 excl = pre + isc - s;
    off[2 * t] = excl;
    off[2 * t + 1] = excl + a;
    __syncthreads();
}

__device__ __forceinline__ void edge_at(int i, const int* s1, const int* d1,
    const int* s2, const int* d2, int E1, int T1, int E2, int NR,
    int& s, int& key)
{
    if (i < T1) {
        if (i < E1) { s = s1[i]; key = d1[i]; }
        else        { s = i - E1; key = i - E1; }
    } else {
        int k = i - T1;
        if (k < E2) { s = s2[k]; key = NR + d2[k]; }
        else        { s = k - E2; key = NR + (k - E2); }
    }
}

// ---- L1: kA2 bucket-sort (no ldsE, 2-pass edge read) ∥ BN ∥ B-pack ∥ dots -------
// blocks [0,A2B): kA2; [A2B,+SB): BN; [+32): pack; [+4): dots (dr1 also T,cb)
// role order: slowest-per-block first (tail minimization).
__global__ __launch_bounds__(256) void k_init(const float* __restrict__ x, int NR,
    float* __restrict__ stats, int SB, int A2B,
    const int* __restrict__ src1, const int* __restrict__ dst1,
    const int* __restrict__ src2, const int* __restrict__ dst2,
    int E1, int L1, int E2, int L2, int NB,
    u32* __restrict__ bucketFill, u32* __restrict__ pairs,
    const float* __restrict__ g2_ws, u16* __restrict__ wsp,
    const float* __restrict__ g1_wd, const float* __restrict__ g1_ad,
    const float* __restrict__ g2_wd, const float* __restrict__ g2_ad,
    const float* __restrict__ g1_ws, const float* __restrict__ g1_as,
    const float* __restrict__ g2_as, const float* __restrict__ g1b)
{
    __shared__ __align__(16) char sm[24144];   // max(kA2 24.1K, BN 20.5K) -> 6 blk/CU
    int t = threadIdx.x;
    int bid = blockIdx.x;
    if (bid < A2B) {
        // ---- kA2 role: LDS counting sort by bucket; edges read twice (L2-warm),
        //      no ldsE staging -> 24.1 KB LDS, higher occupancy ----
        u64* ldsS = (u64*)sm;                    // 2048*8 = 16384
        u32* cntA = (u32*)(ldsS + EB2);          // 2048
        u32* cntB = cntA + 512;                  // 2048
        u32* offL = cntB + 512;                  // 2048
        u32* wsum4 = offL + 512;                 // 16
        u32* gbase = wsum4 + 4;                  // 1600
        for (int i = t; i < 512; i += 256) { cntA[i] = 0; cntB[i] = 0; }
        __syncthreads();
        int T1 = E1 + L1, T = T1 + E2 + L2;
        int base = bid * EB2;
        int nE = T - base; if (nE > EB2) nE = EB2;
        for (int j = t; j < nE; j += 256) {
            int s, key;
            edge_at(base + j, src1, dst1, src2, dst2, E1, T1, E2, NR, s, key);
            atomicAdd(&cntA[key >> 9], 1u);
        }
        __syncthreads();
        scan512f(cntA, offL, wsum4);
        for (int b = t; b < NB; b += 256) {
            u32 c = cntA[b];
            gbase[b] = c ? (((u32)b << CAPSH) + atomicAdd(&bucketFill[b], c)) : 0u;
        }
        // pass 2: re-read edges, place into ldsS at bucketed positions
        for (int j = t; j < nE; j += 256) {
            int s, key;
            edge_at(base + j, src1, dst1, src2, dst2, E1, T1, E2, NR, s, key);
            u32 b = (u32)key >> 9;
            u32 r = atomicAdd(&cntB[b], 1u);
            ldsS[offL[b] + r] = ((u64)(u32)key << 32) | (u32)s;
        }
        __syncthreads();
        // pass 3: contiguous-run global writes of u32-packed (fine,src)
        for (int j = t; j < nE; j += 256) {
            u64 e = ldsS[j];
            u32 key = (u32)(e >> 32);
            u32 b = key >> 9;
            pairs[gbase[b] + ((u32)j - offL[b])] = ((key & 511u) << 17) | (u32)e;
        }
        return;
    }
    if (bid < A2B + SB) {
        // ---- BN stats role (vectorized row load) ----
        float (*L)[DIN] = (float(*)[DIN])sm;
        int r = (bid - A2B) * 256 + t;
        if (r < NR) {
            const float4* xp = (const float4*)(x + (size_t)r * DIN);
            float4 v0 = xp[0], v1 = xp[1], v2 = xp[2], v3 = xp[3], v4 = xp[4];
            L[t][0] = v0.x; L[t][1] = v0.y; L[t][2] = v0.z; L[t][3] = v0.w;
            L[t][4] = v1.x; L[t][5] = v1.y; L[t][6] = v1.z; L[t][7] = v1.w;
            L[t][8] = v2.x; L[t][9] = v2.y; L[t][10] = v2.z; L[t][11] = v2.w;
            L[t][12] = v3.x; L[t][13] = v3.y; L[t][14] = v3.z; L[t][15] = v3.w;
            L[t][16] = v4.x; L[t][17] = v4.y; L[t][18] = v4.z; L[t][19] = v4.w;
        } else {
            #pragma unroll
            for (int k = 0; k < DIN; k++) L[t][k] = 0.f;
        }
        __syncthreads();
        if (t < 210) {
            int p = 0, q = t;
            while (q >= DIN - p) { q -= (DIN - p); p++; }
            q += p;
            float acc = 0.f;
            for (int rr = 0; rr < 256; rr++) acc += L[rr][p] * L[rr][q];
            atomicAdd(&stats[p * DIN + q], acc);
            if (p != q) atomicAdd(&stats[q * DIN + p], acc);
        } else if (t < 230) {
            int k = t - 210;
            float acc = 0.f;
            for (int rr = 0; rr < 256; rr++) acc += L[rr][k];
            atomicAdd(&stats[400 + k], acc);
        }
        return;
    }
    if (bid < A2B + SB + 32) {
        // ---- B-pack role (32 blocks) ----
        int idx0 = ((bid - A2B - SB) * 256 + t) * 4;
        #pragma unroll
        for (int i = 0; i < 4; i++) {
            int flat = idx0 + i;           // [nt(16)][kb(4)][lane(64)][j(8)]
            int j = flat & 7;
            int lane = (flat >> 3) & 63;
            int kb = (flat >> 9) & 3;
            int nt = flat >> 11;
            int k = kb * 32 + (lane >> 4) * 8 + j;
            int n = nt * 16 + (lane & 15);
            wsp[flat] = f2bf_rne(g2_ws[k * HC + n]);
        }
        return;
    }
    // ---- attention dot role (4 blocks) ----
    // dr0: vd1=g1_wd·g1_ad  dr1: vd2=g2_wd·g2_ad (+T,+cb)  dr2: u1  dr3: u2
    int dr = bid - A2B - SB - 32;
    const float* wm = (dr == 0) ? g1_wd : (dr == 1) ? g2_wd : (dr == 2) ? g1_ws : g2_ws;
    const float* am = (dr == 0) ? g1_ad : (dr == 1) ? g2_ad : (dr == 2) ? g1_as : g2_as;
    int obase = (dr == 0) ? 676 : (dr == 1) ? 932 : (dr == 2) ? 1200 : 1456;
    float* vd2l = (float*)sm;
    float acc = 0.f;
    {
        int k = t >> 1, h = t & 1;
        const float4* wp = (const float4*)(wm + k * HC + h * C);
        const float4* ap = (const float4*)(am + h * C);
        #pragma unroll 4
        for (int q = 0; q < 32; q++) {
            float4 xv = wp[q], yv = ap[q];
            acc += xv.x * yv.x + xv.y * yv.y + xv.z * yv.z + xv.w * yv.w;
        }
        stats[obase + t] = acc;
    }
    if (dr == 1) {
        vd2l[t] = acc;
        __syncthreads();
        // T[k*4+h*2+h'] = sum_c g1_ws[k][h*C+c] * vd2[c*2+h']
        int k = t >> 1, h = t & 1;
        const float4* ws1p = (const float4*)(g1_ws + k * HC + h * C);
        float t0 = 0.f, t1 = 0.f;
        #pragma unroll 4
        for (int q = 0; q < 32; q++) {
            float4 wv = ws1p[q];
            int c = q * 4;
            t0 += wv.x * vd2l[(c + 0) * 2 + 0] + wv.y * vd2l[(c + 1) * 2 + 0]
                + wv.z * vd2l[(c + 2) * 2 + 0] + wv.w * vd2l[(c + 3) * 2 + 0];
            t1 += wv.x * vd2l[(c + 0) * 2 + 1] + wv.y * vd2l[(c + 1) * 2 + 1]
                + wv.z * vd2l[(c + 2) * 2 + 1] + wv.w * vd2l[(c + 3) * 2 + 1];
        }
        stats[1712 + t * 2 + 0] = t0;
        stats[1712 + t * 2 + 1] = t1;
        if (t < 2) {
            float cb = 0.f;
            for (int k2 = 0; k2 < C; k2++) cb += g1b[k2] * vd2l[k2 * 2 + t];
            stats[1188 + t] = cb;
        }
    }
}

// ---------------- L2: kB fine sort ∥ user hs ∥ r0f (inline fold) ∥ ing ------------
// blocks [0,NB): kB; [NB,+HB): hs; [+R0B): r0f; [+IB): ing   (slowest first)
__global__ __launch_bounds__(256) void k_fin(const u32* __restrict__ pairs,
    const u32* __restrict__ bucketFill, int n2, int NB, int HB, int R0B,
    int* __restrict__ off2, int* __restrict__ sorted,
    const float* __restrict__ x, int NR, const float* __restrict__ stats,
    const float* __restrict__ W, const float* __restrict__ gamma,
    const float* __restrict__ beta, float invN,
    float* __restrict__ a_d, float* __restrict__ advd,
    const float* __restrict__ ing_table, const int* __restrict__ ing_ids, int NI,
    float* __restrict__ a_si, float* __restrict__ psi,
    const float* __restrict__ user_table, const int* __restrict__ user_ids, int NU,
    const u16* __restrict__ wsp, u16* __restrict__ hs16, float* __restrict__ a_su)
{
    __shared__ __align__(16) char sm[30736];
    int t = threadIdx.x;
    int bid = blockIdx.x;
    if (bid < NB) {
        u32* cntA = (u32*)sm;          // 2048
        u32* cntB = cntA + 512;        // 2048
        u32* offL = cntB + 512;        // 2048
        u32* wsum4 = offL + 512;       // 16
        u32* ldsS = wsum4 + 4;         // 6144*4 = 24576
        int b = bid;
        u32 beg = (u32)b << CAPSH;
        u32 fill = bucketFill[b];
        u32 end = beg + fill;
        int dstBase = b << 9;
        for (int i = t; i < 512; i += 256) { cntA[i] = 0; cntB[i] = 0; }
        __syncthreads();
        for (u32 j = beg + t; j < end; j += 256) {
            u32 fine = pairs[j] >> 17;
            atomicAdd(&cntA[fine], 1u);
        }
        __syncthreads();
        scan512f(cntA, offL, wsum4);
        for (int d = t; d < 512; d += 256) {
            int gk = dstBase + d;
            if (gk < n2) {
                int s0 = (int)(beg + offL[d]);
                off2[2 * gk] = s0;
                off2[2 * gk + 1] = s0 + (int)cntA[d];
            }
        }
        bool fast = fill <= 6144u;
        __syncthreads();
        for (u32 j = beg + t; j < end; j += 256) {
            u32 p = pairs[j];
            u32 d = p >> 17;
            u32 r = atomicAdd(&cntB[d], 1u);
            u32 pos = offL[d] + r;
            u32 src = p & 0x1FFFFu;
            if (fast) ldsS[pos] = src;
            else sorted[beg + pos] = (int)src;
        }
        __syncthreads();
        if (fast) {
            for (u32 j = t; j < fill; j += 256) sorted[beg + j] = (int)ldsS[j];
        }
        return;
    }
    if (bid < NB + HB) {
        // ---- user hs MFMA role ----
        u16* A = (u16*)sm;                       // 32*136*2 = 8704 B
        float* u2s = (float*)(sm + 8704);        // 1024 B
        u2s[t] = stats[1456 + t];
        int rowBase = (bid - NB) * 32;
        int r = t >> 3, cg = t & 7;
        int row = rowBase + r;
        float xv[16];
        if (row < NU) {
            const float* xp = user_table + (size_t)user_ids[row] * C + cg * 16;
            #pragma unroll
            for (int q = 0; q < 4; q++) {
                float4 v = ((const float4*)xp)[q];
                xv[q * 4 + 0] = v.x; xv[q * 4 + 1] = v.y;
                xv[q * 4 + 2] = v.z; xv[q * 4 + 3] = v.w;
            }
        } else {
            #pragma unroll
            for (int q = 0; q < 16; q++) xv[q] = 0.f;
        }
        float ss = 0.f;
        #pragma unroll
        for (int q = 0; q < 16; q++) ss += xv[q] * xv[q];
        #pragma unroll
        for (int m = 1; m <= 4; m <<= 1) ss += __shfl_xor(ss, m);
        float nn = sqrtf(ss);
        float f = (nn > 1.f) ? 1.f / (nn + 1e-7f) : 1.f;
        float as0 = 0.f, as1 = 0.f;
        #pragma unroll
        for (int q = 0; q < 16; q++) {
            xv[q] *= f;
            int k = cg * 16 + q;
            as0 += xv[q] * u2s[k * 2 + 0];
            as1 += xv[q] * u2s[k * 2 + 1];
        }
        #pragma unroll
        for (int m = 1; m <= 4; m <<= 1) {
            as0 += __shfl_xor(as0, m); as1 += __shfl_xor(as1, m);
        }
        if (cg == 0 && row < NU) ((float2*)a_su)[row] = make_float2(as0, as1);
        {
            union { u16 h[16]; uint4 u4[2]; } pk;
            #pragma unroll
            for (int q = 0; q < 16; q++) pk.h[q] = f2bf_rne(xv[q]);
            uint4* dst = (uint4*)&A[r * 136 + cg * 16];
            dst[0] = pk.u4[0];
            dst[1] = pk.u4[1];
        }
        __syncthreads();
        int w = t >> 6, l = t & 63;
        int m15 = l & 15, q4 = l >> 4;
        bf16x8 afrag[2][4];
        #pragma unroll
        for (int mt = 0; mt < 2; mt++)
            #pragma unroll
            for (int kb = 0; kb < 4; kb++)
                afrag[mt][kb] = *(const bf16x8*)&A[(mt * 16 + m15) * 136 + kb * 32 + q4 * 8];
        f32x4 acc[2][4];
        #pragma unroll
        for (int mt = 0; mt < 2; mt++)
            #pragma unroll
            for (int i = 0; i < 4; i++) acc[mt][i] = (f32x4){0.f, 0.f, 0.f, 0.f};
        #pragma unroll
        for (int kb = 0; kb < 4; kb++) {
            #pragma unroll
            for (int i = 0; i < 4; i++) {
                int nt = w * 4 + i;
                bf16x8 bfrag = *(const bf16x8*)&wsp[((nt * 4 + kb) * 64 + l) * 8];
                acc[0][i] = __builtin_amdgcn_mfma_f32_16x16x32_bf16(afrag[0][kb], bfrag, acc[0][i], 0, 0, 0);
                acc[1][i] = __builtin_amdgcn_mfma_f32_16x16x32_bf16(afrag[1][kb], bfrag, acc[1][i], 0, 0, 0);
            }
        }
        #pragma unroll
        for (int mt = 0; mt < 2; mt++) {
            #pragma unroll
            for (int i = 0; i < 4; i++) {
                int col = (w * 4 + i) * 16 + m15;
                #pragma unroll
                for (int rr = 0; rr < 4; rr++) {
                    int rw = rowBase + mt * 16 + q4 * 4 + rr;
                    if (rw < NU) hs16[(size_t)rw * HC + col] = f2bf_rne(acc[mt][i][rr]);
                }
            }
        }
        return;
    }
    if (bid < NB + HB + R0B) {
        // ---- r0f GEMV role with per-block inline BN fold + fv ----
        float* Sm   = (float*)sm;          // 420
        float* Wm   = Sm + 420;            // 2560
        float* vd1s = Wm + 2560;           // 256
        float* vd2s = vd1s + 256;          // 256
        float* sS   = vd2s + 256;          // 128
        float* sSh  = sS + 128;            // 128
        float* fv   = sSh + 128;           // 84
        for (int i = t; i < 420; i += 256) Sm[i] = stats[i];
        for (int i = t; i < DIN * C; i += 256) Wm[i] = W[i];
        vd1s[t] = stats[676 + t];
        vd2s[t] = stats[932 + t];
        __syncthreads();
        if (t < C) {
            float w[DIN];
            #pragma unroll
            for (int k = 0; k < DIN; k++) w[k] = Wm[k * C + t];
            float mb = 0.f;
            #pragma unroll
            for (int k = 0; k < DIN; k++) mb += Sm[400 + k] * invN * w[k];
            float e2 = 0.f;
            for (int p = 0; p < DIN; p++) {
                float acc2 = 0.f;
                #pragma unroll
                for (int q = 0; q < DIN; q++) acc2 += Sm[p * DIN + q] * w[q];
                e2 += w[p] * acc2;
            }
            e2 *= invN;
            float var = e2 - mb * mb;
            float s = gamma[t] * rsqrtf(var + 1e-5f);
            sS[t] = s;
            sSh[t] = beta[t] - s * mb;   // b_rl cancels inside BN
        }
        __syncthreads();
        if (t < 80) {
            int k = t >> 2, h4 = t & 3, h = h4 & 1;
            const float* vs = (h4 < 2) ? vd1s : vd2s;
            float acc = 0.f;
            for (int c = 0; c < C; c++) acc += sS[c] * Wm[k * C + c] * vs[c * 2 + h];
            fv[t] = acc;
        } else if (t < 84) {
            int h4 = t - 80, h = h4 & 1;
            const float* vs = (h4 < 2) ? vd1s : vd2s;
            float acc = 0.f;
            for (int c = 0; c < C; c++) acc += sSh[c] * vs[c * 2 + h];
            fv[t] = acc;
        }
        __syncthreads();
        int r = (bid - NB - HB) * 256 + t;
        if (r < NR) {
            const float4* xp = (const float4*)(x + (size_t)r * DIN);
            float4 v0 = xp[0], v1 = xp[1], v2 = xp[2], v3 = xp[3], v4 = xp[4];
            float xv[20] = {v0.x, v0.y, v0.z, v0.w, v1.x, v1.y, v1.z, v1.w,
                            v2.x, v2.y, v2.z, v2.w, v3.x, v3.y, v3.z, v3.w,
                            v4.x, v4.y, v4.z, v4.w};
            float a0 = 0.f, a1 = 0.f, b0 = 0.f, b1 = 0.f;
            #pragma unroll
            for (int k = 0; k < DIN; k++) {
                float xvk = xv[k];
                a0 += xvk * fv[k * 4 + 0];
                a1 += xvk * fv[k * 4 + 1];
                b0 += xvk * fv[k * 4 + 2];
                b1 += xvk * fv[k * 4 + 3];
            }
            ((float2*)a_d)[r]  = make_float2(a0 + fv[80], a1 + fv[81]);
            ((float2*)advd)[r] = make_float2(b0 + fv[82], b1 + fv[83]);
        }
        return;
    }
    // ---- ingredient role ----
    {
        float* u1s = (float*)sm;
        float* Ts  = u1s + 256;
        u1s[t] = stats[1200 + t];
        Ts[t] = stats[1712 + t];
        Ts[256 + t] = stats[1968 + t];
        __syncthreads();
        int r = t >> 3, cg = t & 7;
        int row = (bid - NB - HB - R0B) * 32 + r;
        float as0 = 0.f, as1 = 0.f, p00 = 0.f, p01 = 0.f, p10 = 0.f, p11 = 0.f;
        if (row < NI) {
            const float* xp = ing_table + (size_t)ing_ids[row] * C + cg * 16;
            #pragma unroll
            for (int q = 0; q < 4; q++) {
                float4 v = ((const float4*)xp)[q];
                float xvv[4] = {v.x, v.y, v.z, v.w};
                #pragma unroll
                for (int jj = 0; jj < 4; jj++) {
                    int k = cg * 16 + q * 4 + jj;
                    float xx = xvv[jj];
                    as0 += xx * u1s[k * 2 + 0];
                    as1 += xx * u1s[k * 2 + 1];
                    p00 += xx * Ts[k * 4 + 0];
                    p01 += xx * Ts[k * 4 + 1];
                    p10 += xx * Ts[k * 4 + 2];
                    p11 += xx * Ts[k * 4 + 3];
                }
            }
        }
        #pragma unroll
        for (int m = 1; m <= 4; m <<= 1) {
            as0 += __shfl_xor(as0, m); as1 += __shfl_xor(as1, m);
            p00 += __shfl_xor(p00, m); p01 += __shfl_xor(p01, m);
            p10 += __shfl_xor(p10, m); p11 += __shfl_xor(p11, m);
        }
        if (cg == 0 && row < NI) {
            ((float2*)a_si)[row] = make_float2(as0, as1);
            float4 pv; pv.x = p00; pv.y = p01; pv.z = p10; pv.w = p11;
            ((float4*)psi)[row] = pv;
        }
    }
}

// ---------------- L3: fused GAT1+GAT2, TWO dsts per wave (half-wave each) ---------
// Half-wave (32 lanes) owns one dst. All __shfl executed UNCONDITIONALLY
// (divergent-shfl from EXEC-masked source lanes is undefined on CDNA).
__global__ __launch_bounds__(256) void k_agg(const int* __restrict__ off2, const int* __restrict__ sorted,
    const float* __restrict__ a_si, const float* __restrict__ psi,
    const float* __restrict__ a_d1, const float* __restrict__ advd,
    const float* __restrict__ cb,
    const float* __restrict__ a_su, const u16* __restrict__ hs16,
    const float* __restrict__ bias, int NR, float* __restrict__ out)
{
    int wave = threadIdx.x >> 6, lane = threadIdx.x & 63;
    int g = lane >> 5, lg = lane & 31;
    int d = blockIdx.x * 8 + wave * 2 + g;
    bool dv = d < NR;
    int dd = dv ? d : NR - 1;
    int sbase = lane & 32;                 // shuffle base of own half
    // ---------- phase 1: GAT1 psi aggregation (per half-wave) ----------
    int beg = off2[2 * dd];
    int end = dv ? off2[2 * dd + 1] : beg;
    float ad0 = a_d1[dd * 2 + 0], ad1 = a_d1[dd * 2 + 1];
    float w0s = 0.f, w1s = 0.f, a00 = 0.f, a01 = 0.f, a10 = 0.f, a11 = 0.f;
    for (int j = beg + lg; j < end; j += 32) {
        int s = sorted[j];
        float2 as = ((const float2*)a_si)[s];
        float e0 = as.x + ad0; e0 = (e0 >= 0.f) ? e0 : 0.2f * e0;
        float e1 = as.y + ad1; e1 = (e1 >= 0.f) ? e1 : 0.2f * e1;
        float x0 = __expf(e0), x1 = __expf(e1);
        float4 p = ((const float4*)psi)[s];
        w0s += x0; w1s += x1;
        a00 += x0 * p.x; a01 += x0 * p.y;
        a10 += x1 * p.z; a11 += x1 * p.w;
    }
    #pragma unroll
    for (int o = 1; o < 32; o <<= 1) {     // stays within own 32-lane half
        w0s += __shfl_xor(w0s, o); w1s += __shfl_xor(w1s, o);
        a00 += __shfl_xor(a00, o); a01 += __shfl_xor(a01, o);
        a10 += __shfl_xor(a10, o); a11 += __shfl_xor(a11, o);
    }
    float inv0g = 1.f / (w0s + 1e-16f), inv1g = 1.f / (w1s + 1e-16f);
    float r0 = advd[dd * 2 + 0] + cb[0] + 0.5f * (a00 * inv0g + a10 * inv1g);
    float r1 = advd[dd * 2 + 1] + cb[1] + 0.5f * (a01 * inv0g + a11 * inv1g);
    // ---------- phase 2: GAT2 hs16 row gather (uint4, per half-wave) ----------
    int i2 = NR + dd;
    int beg2 = off2[2 * i2];
    int end2 = dv ? off2[2 * i2 + 1] : beg2;
    int head = lg >> 4, hq = lg & 15;
    u32 laneoff = (u32)(head * 256 + hq * 16);
    float wsum = 0.f;
    float acc[8];
    #pragma unroll
    for (int k = 0; k < 8; k++) acc[k] = 0.f;
    const char* hbase = (const char*)hs16;

    for (int base = beg2; base < end2; base += 32) {
        int rem = end2 - base; if (rem > 32) rem = 32;
        int j = lg; if (j >= rem) j = rem - 1;
        int sp = sorted[base + j];
        u32 boff = ((u32)sp) << 9;
        float2 av = ((const float2*)a_su)[sp];
        float e0 = av.x + r0; e0 = (e0 >= 0.f) ? e0 : 0.2f * e0;
        float e1 = av.y + r1; e1 = (e1 >= 0.f) ? e1 : 0.2f * e1;
        float w0 = __expf(e0), w1 = __expf(e1);
        for (int e = 0; e < rem; e++) {
            int srcl = sbase + e;
            u32 bo = __shfl(boff, srcl);
            float W0 = __shfl(w0, srcl);    // both shuffles unconditional:
            float W1 = __shfl(w1, srcl);    // all source lanes active
            float W = head ? W1 : W0;       // select AFTER the shuffles
            uint4 gg = *(const uint4*)(hbase + (bo + laneoff));
            wsum += W;
            acc[0] += W * bfbits2f(gg.x & 0xFFFFu);
            acc[1] += W * __uint_as_float(gg.x & 0xFFFF0000u);
            acc[2] += W * bfbits2f(gg.y & 0xFFFFu);
            acc[3] += W * __uint_as_float(gg.y & 0xFFFF0000u);
            acc[4] += W * bfbits2f(gg.z & 0xFFFFu);
            acc[5] += W * __uint_as_float(gg.z & 0xFFFF0000u);
            acc[6] += W * bfbits2f(gg.w & 0xFFFFu);
            acc[7] += W * __uint_as_float(gg.w & 0xFFFF0000u);
        }
    }
    float inv = 1.f / (wsum + 1e-16f);
    // head mean: lane lg and lg^16 hold the two heads, same channels
    #pragma unroll
    for (int k = 0; k < 8; k++) {
        float v = acc[k] * inv;
        acc[k] = 0.5f * (v + __shfl_xor(v, 16));
    }
    if (dv && head == 0) {
        const float4* b4 = (const float4*)bias;
        float4 bb0 = b4[hq * 2], bb1 = b4[hq * 2 + 1];
        float4 o0, o1;
        o0.x = acc[0] + bb0.x; o0.y = acc[1] + bb0.y;
        o0.z = acc[2] + bb0.z; o0.w = acc[3] + bb0.w;
        o1.x = acc[4] + bb1.x; o1.y = acc[5] + bb1.y;
        o1.z = acc[6] + bb1.z; o1.w = acc[7] + bb1.w;
        float4* op = (float4*)(out + (size_t)d * C + hq * 8);
        op[0] = o0; op[1] = o1;
    }
}

extern "C" void kernel_launch(void* const* d_in, const int* in_sizes, int n_in,
                              void* d_out, int out_size, void* d_ws, size_t ws_size,
                              hipStream_t stream) {
    const int*   user_ids       = (const int*)d_in[0];
    const int*   ingredient_ids = (const int*)d_in[1];
    const float* recipe_x       = (const float*)d_in[2];
    const int*   ing_src        = (const int*)d_in[3];
    const int*   ing_dst        = (const int*)d_in[4];
    const int*   ub_src         = (const int*)d_in[5];
    const int*   ub_dst         = (const int*)d_in[6];
    const float* user_table     = (const float*)d_in[7];
    const float* ing_table      = (const float*)d_in[8];
    const float* W_rl           = (const float*)d_in[9];
    const float* bn_gamma       = (const float*)d_in[11];
    const float* bn_beta        = (const float*)d_in[12];
    const float* g1_ws          = (const float*)d_in[13];
    const float* g1_wd          = (const float*)d_in[14];
    const float* g1_as          = (const float*)d_in[15];
    const float* g1_ad          = (const float*)d_in[16];
    const float* g1_b           = (const float*)d_in[17];
    const float* g2_ws          = (const float*)d_in[18];
    const float* g2_wd          = (const float*)d_in[19];
    const float* g2_as          = (const float*)d_in[20];
    const float* g2_ad          = (const float*)d_in[21];
    const float* g2_b           = (const float*)d_in[22];

    int NU = in_sizes[0];
    int NI = in_sizes[1];
    int NR = in_sizes[2] / DIN;
    int E1 = in_sizes[3];
    int E2 = in_sizes[5];
    int Nmax = (NI > NU) ? NI : NU;
    int L1 = (NI < NR) ? NI : NR;
    int L2 = (NU < NR) ? NU : NR;
    int Etot = E1 + L1 + E2 + L2;
    int n2 = 2 * NR;
    int NB = (n2 + 511) >> 9;

    char* w = (char*)d_ws;
    u16*   hs16  = (u16*)w;    w += (size_t)Nmax * HC * 2;
    float* a_si  = (float*)w;  w += (size_t)NI * 2 * 4;
    float* a_su  = (float*)w;  w += (size_t)NU * 2 * 4;
    float* psi   = (float*)w;  w += (size_t)NI * 4 * 4;
    float* a_d   = (float*)w;  w += (size_t)NR * 2 * 4;
    float* advd  = (float*)w;  w += (size_t)NR * 2 * 4;
    float* stats = (float*)w;  w += 2432 * 4;
    u32*   bucketFill = (u32*)w; w += MAXNB * 4;     // adjacent to stats: one memset
    u16*   wsp   = (u16*)w;    w += 32768 * 2;
    int*   off2  = (int*)w;    w += (size_t)(2 * n2) * 4;
    int*   sorted= (int*)w;    w += (size_t)NB * CAP * 4;
    u32*   pairs = (u32*)w;    w += (size_t)NB * CAP * 4;

    hipMemsetAsync(stats, 0, (2432 + MAXNB) * 4, stream);

    int SB  = (NR + 255) / 256;
    int A2B = (Etot + EB2 - 1) / EB2;
    // L1: kA2 bucket sort ∥ BN stats ∥ B-pack ∥ attention dots (+T,+cb)
    k_init<<<A2B + SB + 32 + 4, 256, 0, stream>>>(recipe_x, NR, stats, SB, A2B,
                                              ing_src, ing_dst, ub_src, ub_dst,
                                              E1, L1, E2, L2, NB,
                                              bucketFill, pairs, g2_ws, wsp,
                                              g1_wd, g1_ad, g2_wd, g2_ad,
                                              g1_ws, g1_as, g2_as, g1_b);
    // L2: kB fine sort ∥ user hs MFMA ∥ r0f (inline fold) ∥ ingredient psi
    int R0B = (NR + 255) / 256;
    int IB  = (NI + 31) / 32;
    int HB  = (NU + 31) / 32;
    k_fin<<<NB + HB + R0B + IB, 256, 0, stream>>>(pairs, bucketFill, n2, NB, HB, R0B,
                                                  off2, sorted,
                                                  recipe_x, NR, stats,
                                                  W_rl, bn_gamma, bn_beta, 1.0f / NR,
                                                  a_d, advd,
                                                  ing_table, ingredient_ids, NI, a_si, psi,
                                                  user_table, user_ids, NU,
                                                  wsp, hs16, a_su);
    // L3: fused GAT1 + GAT2 aggregation, 2 dsts per wave
    k_agg<<<(NR + 7) / 8, 256, 0, stream>>>(off2, sorted, a_si, psi, a_d, advd,
                                            stats + 1188, a_su, hs16, g2_b, NR,
                                            (float*)d_out);
}